// Round 10
// baseline (221.646 us; speedup 1.0000x reference)
//
#include <hip/hip_runtime.h>
#include <hip/hip_bf16.h>

// Problem constants (fixed shapes)
#define BATCH 2
#define SEQ   2048
#define EMB   1024
#define DATTN 1024
#define NH    16
#define HD    64
#define MM    (BATCH*SEQ)        // 4096 rows
#define SCALE 0.03125f           // 1/sqrt(1024), exact power of 2
#define QSCALE 0.0450842200278f  // SCALE * log2(e): softmax runs in exp2 domain
#define MINIT -1.0e30f
#define ROPE_COEF 0.41524101186f // (2/64)*log2(10000)

using bf16x8 = __attribute__((ext_vector_type(8))) short;   // 8 bf16 (4 VGPRs)
using f32x4  = __attribute__((ext_vector_type(4))) float;   // MFMA C/D

__device__ inline short f2bf(float x) {
    __hip_bfloat16 b = __float2bfloat16(x);
    return *reinterpret_cast<short*>(&b);
}

// native v_exp_f32 (exp2). NOT libm exp2f (__ocml fixups cost +9us VALU, R8).
__device__ inline float fexp2(float x) { return __builtin_amdgcn_exp2f(x); }

// async global->LDS, 16 B per lane (wave-uniform LDS base). [m03/m97]
__device__ inline void gl_lds16(const short* g, short* l) {
    __builtin_amdgcn_global_load_lds(
        (const __attribute__((address_space(1))) unsigned int*)g,
        (__attribute__((address_space(3))) unsigned int*)l, 16, 0, 0);
}

// ---------------- fp32 -> bf16 pre-convert (weights only; q/k/v fused into proj) ----------------
__global__ __launch_bounds__(256)
void cvt_w(const float* __restrict__ Wq, const float* __restrict__ Wk,
           const float* __restrict__ Wv, const float* __restrict__ Wo,
           short* __restrict__ dst)
{
    const long WSZ = (long)DATTN * EMB;   // 1,048,576
    const long i = ((long)blockIdx.x * 256 + threadIdx.x) * 4;
    const int seg = (int)(i / WSZ);
    const long off = i - (long)seg * WSZ;
    const float* s = (seg == 0) ? Wq : (seg == 1) ? Wk : (seg == 2) ? Wv : Wo;
    float4 x = *(const float4*)(s + off);
    short4 y;
    y.x = f2bf(x.x); y.y = f2bf(x.y); y.z = f2bf(x.z); y.w = f2bf(x.w);
    *(short4*)(dst + i) = y;
}

// ---------------- staging helpers ----------------
// BK=64 bf16 staging: 128x64 tile, linear LDS dest, XOR pre-swizzled source chunk
// slot^(row&7) (rule-21 both-sides; reads apply the same XOR -> 2-way = free).
__device__ inline void stage_tile64(const short* g, short* lds, int tid) {
    #pragma unroll
    for (int c = 0; c < 4; ++c) {
        const int cc   = c * 256 + tid;       // 16B-chunk index 0..1023
        const int row  = cc >> 3;             // 0..127
        const int slot = cc & 7;              // 0..7
        const int ssl  = slot ^ (row & 7);    // pre-swizzled source chunk
        gl_lds16(g + (long)row * EMB + ssl * 8, lds + ((cc & ~63) << 3));
    }
}

// 64x64 tile variant (512 chunks, 2 per thread), same swizzle.
__device__ inline void stage_tile64h(const short* g, short* lds, int tid) {
    #pragma unroll
    for (int c = 0; c < 2; ++c) {
        const int cc   = c * 256 + tid;       // 0..511
        const int row  = cc >> 3;             // 0..63
        const int ssl  = (cc & 7) ^ (row & 7);
        gl_lds16(g + (long)row * EMB + ssl * 8, lds + ((cc & ~63) << 3));
    }
}

// fp32 A staging with fused bf16 convert: reg-stage (float4 x2) -> cvt -> ds_write
// at the SWIZZLED address (write-side swizzle is fine for plain ds_write; same XOR
// as the fragment reads). Replaces the cvt_all pass over q/k/v.
__device__ inline void stage_tileA_f32(const float* g, short* lds, int tid) {
    #pragma unroll
    for (int c = 0; c < 4; ++c) {
        const int cc   = c * 256 + tid;       // 16B-bf16-chunk 0..1023
        const int row  = cc >> 3;             // 0..127
        const int slot = cc & 7;              // 0..7
        const float* src = g + (long)row * EMB + slot * 8;
        const float4 xa = *(const float4*)(src);
        const float4 xb = *(const float4*)(src + 4);
        short4 lo, hi;
        lo.x = f2bf(xa.x); lo.y = f2bf(xa.y); lo.z = f2bf(xa.z); lo.w = f2bf(xa.w);
        hi.x = f2bf(xb.x); hi.y = f2bf(xb.y); hi.z = f2bf(xb.z); hi.w = f2bf(xb.w);
        short* d = lds + row * 64 + (slot ^ (row & 7)) * 8;
        *(short4*)(d)     = lo;
        *(short4*)(d + 4) = hi;
    }
}

// ---------------- fused Q/K/V projection, BK=64, RoPE epilogue ----------------
// A-side reads fp32 q/k/v directly (fused convert, swizzled ds_write); B-side
// stays gl_lds16 from pre-converted weights. Q/K compute C^T (mfma(bfr,af)) so
// the rotary pair is IN-LANE; Q pre-scaled by log2(e) for exp2-domain softmax.
__global__ __launch_bounds__(256)
void gemm_proj_bf16(const float* __restrict__ qf32, const float* __restrict__ kf32,
                    const float* __restrict__ vf32,
                    const short* __restrict__ wqb, const short* __restrict__ wkb,
                    const short* __restrict__ wvb,
                    short* __restrict__ Qb, short* __restrict__ Kb,
                    short* __restrict__ Vtb)
{
    const float* A; const short* B;
    if (blockIdx.z == 0)      { A = qf32; B = wqb; }
    else if (blockIdx.z == 1) { A = kf32; B = wkb; }
    else                      { A = vf32; B = wvb; }
    const bool isv = (blockIdx.z == 2);

    __shared__ short sA[128 * 64];   // 16 KB
    __shared__ short sB[128 * 64];   // 16 KB

    const int tid  = threadIdx.x;
    const int wave = tid >> 6, lane = tid & 63;
    const int quad = lane >> 4, l16 = lane & 15;
    const int wm = (wave >> 1) * 64, wn = (wave & 1) * 64;
    const long m0 = (long)blockIdx.x * 128, n0 = (long)blockIdx.y * 128;
    const int rsw = l16 & 7;         // read-side swizzle (row&7 == l16&7)

    f32x4 acc[4][4];
    #pragma unroll
    for (int i = 0; i < 4; ++i)
        #pragma unroll
        for (int j = 0; j < 4; ++j) acc[i][j] = (f32x4){0.f, 0.f, 0.f, 0.f};

    for (int kt = 0; kt < EMB; kt += 64) {
        __syncthreads();
        stage_tileA_f32(A + m0 * EMB + kt, sA, tid);
        stage_tile64(B + n0 * EMB + kt, sB, tid);
        __syncthreads();

        #pragma unroll
        for (int kk = 0; kk < 2; ++kk) {
            bf16x8 af[4], bfr[4];
            #pragma unroll
            for (int rt = 0; rt < 4; ++rt)
                af[rt] = *(const bf16x8*)&sA[(wm + rt * 16 + l16) * 64
                         + (((kk << 2) | quad) ^ rsw) * 8];
            #pragma unroll
            for (int ct = 0; ct < 4; ++ct)
                bfr[ct] = *(const bf16x8*)&sB[(wn + ct * 16 + l16) * 64
                          + (((kk << 2) | quad) ^ rsw) * 8];
            if (isv) {
                #pragma unroll
                for (int i = 0; i < 4; ++i)
                    #pragma unroll
                    for (int j = 0; j < 4; ++j)
                        acc[i][j] = __builtin_amdgcn_mfma_f32_16x16x32_bf16(
                            af[i], bfr[j], acc[i][j], 0, 0, 0);
            } else {
                #pragma unroll
                for (int i = 0; i < 4; ++i)
                    #pragma unroll
                    for (int j = 0; j < 4; ++j)
                        acc[i][j] = __builtin_amdgcn_mfma_f32_16x16x32_bf16(
                            bfr[i], af[j], acc[i][j], 0, 0, 0);
            }
        }
    }

    if (!isv) {
        // Q/K swapped layout: acc[i=dimtile][j=toktile]; row=dim d (regs),
        // col=token (l16). Rotary pair in regs (0,1) and (2,3).
        short* C = (blockIdx.z == 0) ? Qb : Kb;
        const float scl = (blockIdx.z == 0) ? QSCALE : 1.0f;
        #pragma unroll
        for (int i = 0; i < 4; ++i) {
            const int d0  = (int)(n0) + wn + i * 16 + quad * 4;
            const int hh  = d0 >> 6, dd0 = d0 & (HD - 1);
            const float invf0 = exp2f(-ROPE_COEF * (float)(dd0 >> 1));
            const float invf1 = exp2f(-ROPE_COEF * (float)((dd0 >> 1) + 1));
            #pragma unroll
            for (int j = 0; j < 4; ++j) {
                const int tok = (int)(m0) + wm + j * 16 + l16;
                const int bb = tok >> 11, ss = tok & (SEQ - 1);
                float s0, c0, s1, c1;
                __sincosf((float)ss * invf0, &s0, &c0);
                __sincosf((float)ss * invf1, &s1, &c1);
                const f32x4 x = acc[i][j];
                short4 o4;
                o4.x = f2bf((x[0] * c0 - x[1] * s0) * scl);
                o4.y = f2bf((x[0] * s0 + x[1] * c0) * scl);
                o4.z = f2bf((x[2] * c1 - x[3] * s1) * scl);
                o4.w = f2bf((x[2] * s1 + x[3] * c1) * scl);
                *(short4*)&C[(((long)(bb * NH + hh)) << 17)
                             + ((long)ss << 6) + dd0] = o4;
            }
        }
    } else {
        // V original layout: acc[rt=toktile][ct=dimtile]; rows=tokens in regs.
        // Vt[((b*NH+h)*HD + d)*SEQ + s], short4 along tokens.
        #pragma unroll
        for (int rt = 0; rt < 4; ++rt) {
            #pragma unroll
            for (int ct = 0; ct < 4; ++ct) {
                const long row0 = m0 + wm + rt * 16 + quad * 4;
                const long col  = n0 + wn + ct * 16 + l16;
                const int bb = (int)(row0 >> 11), ss = (int)(row0 & (SEQ - 1));
                const int hh = (int)(col >> 6),   dd = (int)(col & (HD - 1));
                short4 s4;
                s4.x = f2bf(acc[rt][ct][0]); s4.y = f2bf(acc[rt][ct][1]);
                s4.z = f2bf(acc[rt][ct][2]); s4.w = f2bf(acc[rt][ct][3]);
                *(short4*)&Vtb[(((long)(bb * NH + hh)) << 17) + ((long)dd << 11) + ss] = s4;
            }
        }
    }
}

// Output GEMM: out = ctx(bf16) @ Wo^T(bf16), out fp32 [4096,1024]
// 128x64 tiles -> 512 blocks = 2/CU; BK=64 + XOR swizzle; dbuf pipeline (R8).
__global__ __launch_bounds__(256)
void gemm_out_bf16(const short* __restrict__ Ab, const short* __restrict__ Bb,
                   float* __restrict__ C)
{
    __shared__ short sA[2][128 * 64];   // 32 KB
    __shared__ short sB[2][64 * 64];    // 16 KB

    const int tid  = threadIdx.x;
    const int wave = tid >> 6, lane = tid & 63;
    const int quad = lane >> 4, l16 = lane & 15;
    const int wm = (wave >> 1) * 64, wn = (wave & 1) * 32;
    const long m0 = (long)blockIdx.x * 128, n0 = (long)blockIdx.y * 64;
    const int rsw = l16 & 7;

    f32x4 acc[4][2];
    #pragma unroll
    for (int i = 0; i < 4; ++i)
        #pragma unroll
        for (int j = 0; j < 2; ++j) acc[i][j] = (f32x4){0.f, 0.f, 0.f, 0.f};

    stage_tile64(Ab + m0 * DATTN, sA[0], tid);
    stage_tile64h(Bb + n0 * DATTN, sB[0], tid);

    #pragma unroll 1
    for (int s = 0; s < 16; ++s) {
        const int pb = s & 1;
        asm volatile("s_waitcnt vmcnt(0)" ::: "memory");
        __builtin_amdgcn_s_barrier();
        if (s + 1 < 16) {
            stage_tile64(Ab + m0 * DATTN + (s + 1) * 64, sA[pb ^ 1], tid);
            stage_tile64h(Bb + n0 * DATTN + (s + 1) * 64, sB[pb ^ 1], tid);
        }

        #pragma unroll
        for (int kk = 0; kk < 2; ++kk) {
            bf16x8 af[4], bfr[2];
            #pragma unroll
            for (int rt = 0; rt < 4; ++rt)
                af[rt] = *(const bf16x8*)&sA[pb][(wm + rt * 16 + l16) * 64
                         + (((kk << 2) | quad) ^ rsw) * 8];
            #pragma unroll
            for (int ct = 0; ct < 2; ++ct)
                bfr[ct] = *(const bf16x8*)&sB[pb][(wn + ct * 16 + l16) * 64
                          + (((kk << 2) | quad) ^ rsw) * 8];
            #pragma unroll
            for (int rt = 0; rt < 4; ++rt)
                #pragma unroll
                for (int ct = 0; ct < 2; ++ct)
                    acc[rt][ct] = __builtin_amdgcn_mfma_f32_16x16x32_bf16(
                        af[rt], bfr[ct], acc[rt][ct], 0, 0, 0);
        }
    }

    #pragma unroll
    for (int rt = 0; rt < 4; ++rt) {
        #pragma unroll
        for (int ct = 0; ct < 2; ++ct) {
            #pragma unroll
            for (int reg = 0; reg < 4; ++reg) {
                const long row = m0 + wm + rt * 16 + quad * 4 + reg;
                const long col = n0 + wn + ct * 16 + l16;
                C[row * EMB + col] = acc[rt][ct][reg];
            }
        }
    }
}

// ---------------- MFMA flash attention: TQ=128, dbuf 64-key pipeline ----------------
// R10 = R9's proven schedule (dbuf staging, one raw s_barrier + vmcnt(0) per tile,
// exp2-domain native-exp softmax) with stream-SEQUENTIAL PV (T15-lite): stream 0's
// softmax+P+PV issue first (vf held in regs), then stream 1's softmax VALU runs
// while PV0's MFMAs drain (separate pipes), then PV1 reuses the held vf. No new
// DS ops; +~32 VGPR. launch_bounds (256,2): grid gives 2 blocks/CU; avoids
// regalloc pressure from the held vf.
#define KLD 64   // K/V LDS row stride (shorts) — linear, swizzle in chunk index
#define PLD 72   // P buffer row stride (shorts)

// stage one 64-key tile of K and V (512 chunks each, 2+2 gl_lds per thread)
__device__ inline void stage_kv64(const short* __restrict__ Kb,
                                  const short* __restrict__ Vtb,
                                  long base, int jb2,
                                  short* skp, short* svp,
                                  int tid, int wave)
{
    #pragma unroll
    for (int c = 0; c < 2; ++c) {
        const int cc  = c * 256 + tid;        // 0..511
        const int row = cc >> 3;              // 0..63
        const int sch = (cc & 7) ^ (row & 7); // pre-swizzled source chunk
        // LDS dest: wave-uniform chunk base (c*256 + wave*64); HW adds lane*16B.
        gl_lds16(Kb + base + (long)(jb2 + row) * HD + sch * 8,
                 skp + ((c * 256 + wave * 64) << 3));
        gl_lds16(Vtb + base + ((long)row << 11) + jb2 + sch * 8,
                 svp + ((c * 256 + wave * 64) << 3));
    }
}

__global__ __launch_bounds__(256, 2)
void flash_attn_mfma(const short* __restrict__ Qb,
                     const short* __restrict__ Kb,
                     const short* __restrict__ Vtb,
                     short* __restrict__ ctx)
{
    // id -> (xcd residue r, pair p, 128-query tile t)
    const int id  = blockIdx.x;           // 0..511
    const int hi  = id >> 8;              // 0 = heavy half, 1 = light half
    const int idx = id & 255;
    const int r   = idx & 7;              // XCD residue
    const int s5  = idx >> 3;             // 0..31
    const int pi  = s5 & 3;               // pair-within-residue
    const int ts8 = s5 >> 2;              // 0..7
    const int p   = r + 8 * pi;           // (b*NH+h) in [0,32)
    const int b   = p >> 4, h = p & 15;
    const int t   = hi ? ts8 : (15 - ts8);

    const int tid = threadIdx.x;
    const int wave = tid >> 6, lane = tid & 63;
    const int quad = lane >> 4, l16 = lane & 15;
    const int r0 = t * 128;

    __shared__ short sk[2][64 * KLD];     // double-buffered K (16 KB)
    __shared__ short sv[2][64 * KLD];     // double-buffered V (16 KB)
    __shared__ short sp[4][32 * PLD];     // per-wave P: rows 0..15 g0, 16..31 g1 (18 KB)

    const long base = ((long)(b * NH + h)) << 17;   // SEQ*HD = 2^17

    // two 16-query groups per wave (contiguous): iq1 = iq0 + 16
    const int iq0 = r0 + wave * 32 + l16;
    const int iq1 = iq0 + 16;
    const int dtile = 2 * t + (wave >> 1);   // this wave's diagonal 64-key tile
    const int rsw = l16 & 7;                 // read-side swizzle (row&7 == l16&7)

    bf16x8 qf0[2], qf1[2];
    #pragma unroll
    for (int tt = 0; tt < 2; ++tt) {
        qf0[tt] = *(const bf16x8*)(Qb + base + (long)iq0 * HD + tt * 32 + quad * 8);
        qf1[tt] = *(const bf16x8*)(Qb + base + (long)iq1 * HD + tt * 32 + quad * 8);
    }

    f32x4 acc0[4], acc1[4];
    #pragma unroll
    for (int ct = 0; ct < 4; ++ct) {
        acc0[ct] = (f32x4){0.f, 0.f, 0.f, 0.f};
        acc1[ct] = (f32x4){0.f, 0.f, 0.f, 0.f};
    }
    float m0 = MINIT, l0 = 0.f;
    float m1 = MINIT, l1 = 0.f;

    const int J = 2 * t + 2;              // 64-key tiles to process (block-uniform)

    stage_kv64(Kb, Vtb, base, 0, sk[0], sv[0], tid, wave);

    #pragma unroll 1
    for (int j2 = 0; j2 < J; ++j2) {
        const int pb = j2 & 1;
        // own loads of buf[pb] (issued a full tile ago) complete, then sync:
        asm volatile("s_waitcnt vmcnt(0)" ::: "memory");
        __builtin_amdgcn_s_barrier();
        // issue next tile's loads into the other buffer (retire under compute)
        if (j2 + 1 < J)
            stage_kv64(Kb, Vtb, base, (j2 + 1) * 64,
                       sk[pb ^ 1], sv[pb ^ 1], tid, wave);

        if (j2 <= dtile) {
            const int jb2 = j2 * 64;
            const short* skh = sk[pb];
            const short* svh = sv[pb];

            // S^T for both groups; K fragments per-ct, shared by both groups.
            f32x4 s0[4], s1[4];
            __builtin_amdgcn_s_setprio(1);
            #pragma unroll
            for (int ct = 0; ct < 4; ++ct) {
                const int rr16 = (ct * 16 + l16) * KLD;
                bf16x8 k0 = *(const bf16x8*)&skh[rr16 + ((quad ^ rsw) << 3)];
                bf16x8 k1 = *(const bf16x8*)&skh[rr16 + (((4 + quad) ^ rsw) << 3)];
                f32x4 z0 = (f32x4){0.f, 0.f, 0.f, 0.f};
                z0 = __builtin_amdgcn_mfma_f32_16x16x32_bf16(k0, qf0[0], z0, 0, 0, 0);
                z0 = __builtin_amdgcn_mfma_f32_16x16x32_bf16(k1, qf0[1], z0, 0, 0, 0);
                s0[ct] = z0;
                f32x4 z1 = (f32x4){0.f, 0.f, 0.f, 0.f};
                z1 = __builtin_amdgcn_mfma_f32_16x16x32_bf16(k0, qf1[0], z1, 0, 0, 0);
                z1 = __builtin_amdgcn_mfma_f32_16x16x32_bf16(k1, qf1[1], z1, 0, 0, 0);
                s1[ct] = z1;
            }
            __builtin_amdgcn_s_setprio(0);

            if (j2 == dtile) {   // diagonal tile: causal mask per group
                #pragma unroll
                for (int ct = 0; ct < 4; ++ct)
                    #pragma unroll
                    for (int rr = 0; rr < 4; ++rr) {
                        const int j = jb2 + ct * 16 + quad * 4 + rr;
                        if (!((j < iq0) || (iq0 == 0 && j == 0)))
                            s0[ct][rr] = -INFINITY;
                        if (!(j < iq1))               // iq1 >= 16, no (0,0) case
                            s1[ct][rr] = -INFINITY;
                    }
            }

            // ---- stream 0: softmax -> P0 -> rescale -> PV0 (vf held in regs) ----
            float mx0 = MINIT;
            #pragma unroll
            for (int ct = 0; ct < 4; ++ct)
                #pragma unroll
                for (int rr = 0; rr < 4; ++rr) mx0 = fmaxf(mx0, s0[ct][rr]);
            mx0 = fmaxf(mx0, __shfl_xor(mx0, 16, 64));
            mx0 = fmaxf(mx0, __shfl_xor(mx0, 32, 64));
            const float mn0 = fmaxf(m0, mx0);
            const float a0 = fexp2(m0 - mn0);
            m0 = mn0;
            float ss0 = 0.f;
            #pragma unroll
            for (int ct = 0; ct < 4; ++ct)
                #pragma unroll
                for (int rr = 0; rr < 4; ++rr) {
                    const float e = fexp2(s0[ct][rr] - mn0);
                    s0[ct][rr] = e;
                    ss0 += e;
                }
            ss0 += __shfl_xor(ss0, 16, 64);
            ss0 += __shfl_xor(ss0, 32, 64);
            l0 = l0 * a0 + ss0;

            short* pw0 = sp[wave];
            #pragma unroll
            for (int ct = 0; ct < 4; ++ct) {
                short4 p4;
                p4.x = f2bf(s0[ct][0]); p4.y = f2bf(s0[ct][1]);
                p4.z = f2bf(s0[ct][2]); p4.w = f2bf(s0[ct][3]);
                *(short4*)&pw0[l16 * PLD + ct * 16 + quad * 4] = p4;
            }
            #pragma unroll
            for (int ct = 0; ct < 4; ++ct)
                #pragma unroll
                for (int rr = 0; rr < 4; ++rr) acc0[ct][rr] *= a0;

            bf16x8 pf00 = *(const bf16x8*)&pw0[l16 * PLD + quad * 8];
            bf16x8 pf01 = *(const bf16x8*)&pw0[l16 * PLD + 32 + quad * 8];

            bf16x8 vf[4][2];
            __builtin_amdgcn_s_setprio(1);
            #pragma unroll
            for (int ct = 0; ct < 4; ++ct) {
                const int rr16 = (ct * 16 + l16) * KLD;
                vf[ct][0] = *(const bf16x8*)&svh[rr16 + ((quad ^ rsw) << 3)];
                vf[ct][1] = *(const bf16x8*)&svh[rr16 + (((4 + quad) ^ rsw) << 3)];
                acc0[ct] = __builtin_amdgcn_mfma_f32_16x16x32_bf16(
                    vf[ct][0], pf00, acc0[ct], 0, 0, 0);
                acc0[ct] = __builtin_amdgcn_mfma_f32_16x16x32_bf16(
                    vf[ct][1], pf01, acc0[ct], 0, 0, 0);
            }
            __builtin_amdgcn_s_setprio(0);

            // ---- stream 1: softmax VALU overlaps PV0 MFMAs in flight ----
            float mx1 = MINIT;
            #pragma unroll
            for (int ct = 0; ct < 4; ++ct)
                #pragma unroll
                for (int rr = 0; rr < 4; ++rr) mx1 = fmaxf(mx1, s1[ct][rr]);
            mx1 = fmaxf(mx1, __shfl_xor(mx1, 16, 64));
            mx1 = fmaxf(mx1, __shfl_xor(mx1, 32, 64));
            const float mn1 = fmaxf(m1, mx1);
            const float a1 = fexp2(m1 - mn1);
            m1 = mn1;
            float ss1 = 0.f;
            #pragma unroll
            for (int ct = 0; ct < 4; ++ct)
                #pragma unroll
                for (int rr = 0; rr < 4; ++rr) {
                    const float e = fexp2(s1[ct][rr] - mn1);
                    s1[ct][rr] = e;
                    ss1 += e;
                }
            ss1 += __shfl_xor(ss1, 16, 64);
            ss1 += __shfl_xor(ss1, 32, 64);
            l1 = l1 * a1 + ss1;

            short* pw1 = sp[wave] + 16 * PLD;
            #pragma unroll
            for (int ct = 0; ct < 4; ++ct) {
                short4 q4;
                q4.x = f2bf(s1[ct][0]); q4.y = f2bf(s1[ct][1]);
                q4.z = f2bf(s1[ct][2]); q4.w = f2bf(s1[ct][3]);
                *(short4*)&pw1[l16 * PLD + ct * 16 + quad * 4] = q4;
            }
            #pragma unroll
            for (int ct = 0; ct < 4; ++ct)
                #pragma unroll
                for (int rr = 0; rr < 4; ++rr) acc1[ct][rr] *= a1;

            bf16x8 pf10 = *(const bf16x8*)&pw1[l16 * PLD + quad * 8];
            bf16x8 pf11 = *(const bf16x8*)&pw1[l16 * PLD + 32 + quad * 8];

            __builtin_amdgcn_s_setprio(1);
            #pragma unroll
            for (int ct = 0; ct < 4; ++ct) {
                acc1[ct] = __builtin_amdgcn_mfma_f32_16x16x32_bf16(
                    vf[ct][0], pf10, acc1[ct], 0, 0, 0);
                acc1[ct] = __builtin_amdgcn_mfma_f32_16x16x32_bf16(
                    vf[ct][1], pf11, acc1[ct], 0, 0, 0);
            }
            __builtin_amdgcn_s_setprio(0);
        }
    }

    // epilogue: acc C-layout row=dim (ct*16+quad*4+reg), col=l16=query
    {
        const float inv0 = 1.f / l0;
        short* orow = ctx + (long)(b * SEQ + iq0) * DATTN + h * HD;
        #pragma unroll
        for (int ct = 0; ct < 4; ++ct) {
            short4 o4;
            o4.x = f2bf(acc0[ct][0] * inv0);
            o4.y = f2bf(acc0[ct][1] * inv0);
            o4.z = f2bf(acc0[ct][2] * inv0);
            o4.w = f2bf(acc0[ct][3] * inv0);
            *(short4*)&orow[ct * 16 + quad * 4] = o4;
        }
    }
    {
        const float inv1 = 1.f / l1;
        short* orow = ctx + (long)(b * SEQ + iq1) * DATTN + h * HD;
        #pragma unroll
        for (int ct = 0; ct < 4; ++ct) {
            short4 o4;
            o4.x = f2bf(acc1[ct][0] * inv1);
            o4.y = f2bf(acc1[ct][1] * inv1);
            o4.z = f2bf(acc1[ct][2] * inv1);
            o4.w = f2bf(acc1[ct][3] * inv1);
            *(short4*)&orow[ct * 16 + quad * 4] = o4;
        }
    }
}

extern "C" void kernel_launch(void* const* d_in, const int* in_sizes, int n_in,
                              void* d_out, int out_size, void* d_ws, size_t ws_size,
                              hipStream_t stream) {
    const float* q  = (const float*)d_in[0];
    const float* k  = (const float*)d_in[1];
    const float* v  = (const float*)d_in[2];
    const float* Wq = (const float*)d_in[3];
    const float* Wk = (const float*)d_in[4];
    const float* Wv = (const float*)d_in[5];
    const float* Wo = (const float*)d_in[6];
    float* out = (float*)d_out;

    // workspace (bf16 shorts), 64 MB:
    // qb|kb|vb (unused, kept for layout) | wqb|wkb|wvb|wob (1M each) |
    // Qb|Kb|Vtb|ctx (4M each)
    const long QKV = (long)MM * EMB;      // 4,194,304
    const long WSZ = (long)DATTN * EMB;   // 1,048,576
    short* basep = (short*)d_ws;
    short* wqb = basep + 3 * QKV;
    short* wkb = wqb + WSZ;
    short* wvb = wkb + WSZ;
    short* wob = wvb + WSZ;
    short* Qb  = wob + WSZ;
    short* Kb  = Qb + QKV;
    short* Vtb = Kb + QKV;
    short* ctx = Vtb + QKV;

    // 1) fp32 -> bf16 pre-convert, WEIGHTS ONLY (q/k/v convert fused into proj)
    cvt_w<<<4096, 256, 0, stream>>>(Wq, Wk, Wv, Wo, wqb);

    // 2) fused Q/K/V projection + RoPE (fp32 A with fused convert, BK=64)
    gemm_proj_bf16<<<dim3(MM / 128, DATTN / 128, 3), 256, 0, stream>>>(
        q, k, v, wqb, wkb, wvb, Qb, Kb, Vtb);

    // 3) flash attention (R9 dbuf schedule + stream-sequential PV, 512 blocks)
    flash_attn_mfma<<<512, 256, 0, stream>>>(Qb, Kb, Vtb, ctx);

    // 4) output GEMM (128x64 tiles, BK=64 swizzled, dbuf pipeline, 512 blocks)
    gemm_out_bf16<<<dim3(MM / 128, EMB / 64), 256, 0, stream>>>(ctx, wob, out);
}

// Round 11
// 207.374 us; speedup vs baseline: 1.0688x; 1.0688x over previous
//
#include <hip/hip_runtime.h>
#include <hip/hip_bf16.h>

// Problem constants (fixed shapes)
#define BATCH 2
#define SEQ   2048
#define EMB   1024
#define DATTN 1024
#define NH    16
#define HD    64
#define MM    (BATCH*SEQ)        // 4096 rows
#define SCALE 0.03125f           // 1/sqrt(1024), exact power of 2
#define QSCALE 0.0450842200278f  // SCALE * log2(e): softmax runs in exp2 domain
#define MINIT -1.0e30f
#define ROPE_COEF 0.41524101186f // (2/64)*log2(10000)

using bf16x8 = __attribute__((ext_vector_type(8))) short;   // 8 bf16 (4 VGPRs)
using f32x4  = __attribute__((ext_vector_type(4))) float;   // MFMA C/D

__device__ inline short f2bf(float x) {
    __hip_bfloat16 b = __float2bfloat16(x);
    return *reinterpret_cast<short*>(&b);
}

// native v_exp_f32 (exp2). NOT libm exp2f (__ocml fixups cost +9us VALU, R8).
__device__ inline float fexp2(float x) { return __builtin_amdgcn_exp2f(x); }

// async global->LDS, 16 B per lane (wave-uniform LDS base). [m03/m97]
__device__ inline void gl_lds16(const short* g, short* l) {
    __builtin_amdgcn_global_load_lds(
        (const __attribute__((address_space(1))) unsigned int*)g,
        (__attribute__((address_space(3))) unsigned int*)l, 16, 0, 0);
}

// ---------------- fp32 -> bf16 pre-convert (q,k,v,Wq,Wk,Wv,Wo) ----------------
// R11: restored from R9. Separate roofline-bound pass + async bf16 staging beats
// fused-but-serialized fp32 staging (R10: proj 45->78us, FETCH +12MB — reverted).
__global__ __launch_bounds__(256)
void cvt_all(const float* __restrict__ q, const float* __restrict__ k,
             const float* __restrict__ v,
             const float* __restrict__ Wq, const float* __restrict__ Wk,
             const float* __restrict__ Wv, const float* __restrict__ Wo,
             short* __restrict__ dst)
{
    const long QKV = (long)MM * EMB;      // 4,194,304
    const long WSZ = (long)DATTN * EMB;   // 1,048,576
    const long i = ((long)blockIdx.x * 256 + threadIdx.x) * 4;
    const float* s;
    long off;
    if (i < 3 * QKV) {
        const int seg = (int)(i / QKV);
        off = i - (long)seg * QKV;
        s = (seg == 0) ? q : (seg == 1) ? k : v;
    } else {
        const long j = i - 3 * QKV;
        const int seg = (int)(j / WSZ);
        off = j - (long)seg * WSZ;
        s = (seg == 0) ? Wq : (seg == 1) ? Wk : (seg == 2) ? Wv : Wo;
    }
    float4 x = *(const float4*)(s + off);
    short4 y;
    y.x = f2bf(x.x); y.y = f2bf(x.y); y.z = f2bf(x.z); y.w = f2bf(x.w);
    *(short4*)(dst + i) = y;
}

// ---------------- staging helpers ----------------
// BK=64 staging: 128x64 tile, linear LDS dest, XOR pre-swizzled source chunk
// slot^(row&7) (rule-21 both-sides; reads apply the same XOR -> 2-way = free).
__device__ inline void stage_tile64(const short* g, short* lds, int tid) {
    #pragma unroll
    for (int c = 0; c < 4; ++c) {
        const int cc   = c * 256 + tid;       // 16B-chunk index 0..1023
        const int row  = cc >> 3;             // 0..127
        const int slot = cc & 7;              // 0..7
        const int ssl  = slot ^ (row & 7);    // pre-swizzled source chunk
        gl_lds16(g + (long)row * EMB + ssl * 8, lds + ((cc & ~63) << 3));
    }
}

// 64x64 tile variant (512 chunks, 2 per thread), same swizzle.
__device__ inline void stage_tile64h(const short* g, short* lds, int tid) {
    #pragma unroll
    for (int c = 0; c < 2; ++c) {
        const int cc   = c * 256 + tid;       // 0..511
        const int row  = cc >> 3;             // 0..63
        const int ssl  = (cc & 7) ^ (row & 7);
        gl_lds16(g + (long)row * EMB + ssl * 8, lds + ((cc & ~63) << 3));
    }
}

// ---------------- fused Q/K/V projection, BK=64, RoPE epilogue (R9) ----------------
// 128x128 tile, 16 K-steps. Q/K compute C^T (mfma(bfr,af)) so the rotary pair is
// IN-LANE (regs 0/1, 2/3): no shfl, 2 sincos per 4 elems, aligned short4 stores.
// Q additionally pre-scaled by log2(e) so flash softmax runs in exp2 domain.
__global__ __launch_bounds__(256)
void gemm_proj_bf16(const short* __restrict__ qb, const short* __restrict__ kb,
                    const short* __restrict__ vb,
                    const short* __restrict__ wqb, const short* __restrict__ wkb,
                    const short* __restrict__ wvb,
                    short* __restrict__ Qb, short* __restrict__ Kb,
                    short* __restrict__ Vtb)
{
    const short* A; const short* B;
    if (blockIdx.z == 0)      { A = qb; B = wqb; }
    else if (blockIdx.z == 1) { A = kb; B = wkb; }
    else                      { A = vb; B = wvb; }
    const bool isv = (blockIdx.z == 2);

    __shared__ short sA[128 * 64];   // 16 KB
    __shared__ short sB[128 * 64];   // 16 KB

    const int tid  = threadIdx.x;
    const int wave = tid >> 6, lane = tid & 63;
    const int quad = lane >> 4, l16 = lane & 15;
    const int wm = (wave >> 1) * 64, wn = (wave & 1) * 64;
    const long m0 = (long)blockIdx.x * 128, n0 = (long)blockIdx.y * 128;
    const int rsw = l16 & 7;         // read-side swizzle (row&7 == l16&7)

    f32x4 acc[4][4];
    #pragma unroll
    for (int i = 0; i < 4; ++i)
        #pragma unroll
        for (int j = 0; j < 4; ++j) acc[i][j] = (f32x4){0.f, 0.f, 0.f, 0.f};

    for (int kt = 0; kt < EMB; kt += 64) {
        __syncthreads();
        stage_tile64(A + m0 * EMB + kt, sA, tid);
        stage_tile64(B + n0 * EMB + kt, sB, tid);
        __syncthreads();

        #pragma unroll
        for (int kk = 0; kk < 2; ++kk) {
            bf16x8 af[4], bfr[4];
            #pragma unroll
            for (int rt = 0; rt < 4; ++rt)
                af[rt] = *(const bf16x8*)&sA[(wm + rt * 16 + l16) * 64
                         + (((kk << 2) | quad) ^ rsw) * 8];
            #pragma unroll
            for (int ct = 0; ct < 4; ++ct)
                bfr[ct] = *(const bf16x8*)&sB[(wn + ct * 16 + l16) * 64
                          + (((kk << 2) | quad) ^ rsw) * 8];
            if (isv) {
                #pragma unroll
                for (int i = 0; i < 4; ++i)
                    #pragma unroll
                    for (int j = 0; j < 4; ++j)
                        acc[i][j] = __builtin_amdgcn_mfma_f32_16x16x32_bf16(
                            af[i], bfr[j], acc[i][j], 0, 0, 0);
            } else {
                #pragma unroll
                for (int i = 0; i < 4; ++i)
                    #pragma unroll
                    for (int j = 0; j < 4; ++j)
                        acc[i][j] = __builtin_amdgcn_mfma_f32_16x16x32_bf16(
                            bfr[i], af[j], acc[i][j], 0, 0, 0);
            }
        }
    }

    if (!isv) {
        // Q/K swapped layout: acc[i=dimtile][j=toktile]; row=dim d (regs),
        // col=token (l16). Rotary pair in regs (0,1) and (2,3).
        short* C = (blockIdx.z == 0) ? Qb : Kb;
        const float scl = (blockIdx.z == 0) ? QSCALE : 1.0f;
        #pragma unroll
        for (int i = 0; i < 4; ++i) {
            const int d0  = (int)(n0) + wn + i * 16 + quad * 4;
            const int hh  = d0 >> 6, dd0 = d0 & (HD - 1);
            const float invf0 = exp2f(-ROPE_COEF * (float)(dd0 >> 1));
            const float invf1 = exp2f(-ROPE_COEF * (float)((dd0 >> 1) + 1));
            #pragma unroll
            for (int j = 0; j < 4; ++j) {
                const int tok = (int)(m0) + wm + j * 16 + l16;
                const int bb = tok >> 11, ss = tok & (SEQ - 1);
                float s0, c0, s1, c1;
                __sincosf((float)ss * invf0, &s0, &c0);
                __sincosf((float)ss * invf1, &s1, &c1);
                const f32x4 x = acc[i][j];
                short4 o4;
                o4.x = f2bf((x[0] * c0 - x[1] * s0) * scl);
                o4.y = f2bf((x[0] * s0 + x[1] * c0) * scl);
                o4.z = f2bf((x[2] * c1 - x[3] * s1) * scl);
                o4.w = f2bf((x[2] * s1 + x[3] * c1) * scl);
                *(short4*)&C[(((long)(bb * NH + hh)) << 17)
                             + ((long)ss << 6) + dd0] = o4;
            }
        }
    } else {
        // V original layout: acc[rt=toktile][ct=dimtile]; rows=tokens in regs.
        // Vt[((b*NH+h)*HD + d)*SEQ + s], short4 along tokens.
        #pragma unroll
        for (int rt = 0; rt < 4; ++rt) {
            #pragma unroll
            for (int ct = 0; ct < 4; ++ct) {
                const long row0 = m0 + wm + rt * 16 + quad * 4;
                const long col  = n0 + wn + ct * 16 + l16;
                const int bb = (int)(row0 >> 11), ss = (int)(row0 & (SEQ - 1));
                const int hh = (int)(col >> 6),   dd = (int)(col & (HD - 1));
                short4 s4;
                s4.x = f2bf(acc[rt][ct][0]); s4.y = f2bf(acc[rt][ct][1]);
                s4.z = f2bf(acc[rt][ct][2]); s4.w = f2bf(acc[rt][ct][3]);
                *(short4*)&Vtb[(((long)(bb * NH + hh)) << 17) + ((long)dd << 11) + ss] = s4;
            }
        }
    }
}

// Output GEMM: out = ctx(bf16) @ Wo^T(bf16), out fp32 [4096,1024]
// 128x64 tiles -> 512 blocks = 2/CU; BK=64 + XOR swizzle; dbuf pipeline (R8).
__global__ __launch_bounds__(256)
void gemm_out_bf16(const short* __restrict__ Ab, const short* __restrict__ Bb,
                   float* __restrict__ C)
{
    __shared__ short sA[2][128 * 64];   // 32 KB
    __shared__ short sB[2][64 * 64];    // 16 KB

    const int tid  = threadIdx.x;
    const int wave = tid >> 6, lane = tid & 63;
    const int quad = lane >> 4, l16 = lane & 15;
    const int wm = (wave >> 1) * 64, wn = (wave & 1) * 32;
    const long m0 = (long)blockIdx.x * 128, n0 = (long)blockIdx.y * 64;
    const int rsw = l16 & 7;

    f32x4 acc[4][2];
    #pragma unroll
    for (int i = 0; i < 4; ++i)
        #pragma unroll
        for (int j = 0; j < 2; ++j) acc[i][j] = (f32x4){0.f, 0.f, 0.f, 0.f};

    stage_tile64(Ab + m0 * DATTN, sA[0], tid);
    stage_tile64h(Bb + n0 * DATTN, sB[0], tid);

    #pragma unroll 1
    for (int s = 0; s < 16; ++s) {
        const int pb = s & 1;
        asm volatile("s_waitcnt vmcnt(0)" ::: "memory");
        __builtin_amdgcn_s_barrier();
        if (s + 1 < 16) {
            stage_tile64(Ab + m0 * DATTN + (s + 1) * 64, sA[pb ^ 1], tid);
            stage_tile64h(Bb + n0 * DATTN + (s + 1) * 64, sB[pb ^ 1], tid);
        }

        #pragma unroll
        for (int kk = 0; kk < 2; ++kk) {
            bf16x8 af[4], bfr[2];
            #pragma unroll
            for (int rt = 0; rt < 4; ++rt)
                af[rt] = *(const bf16x8*)&sA[pb][(wm + rt * 16 + l16) * 64
                         + (((kk << 2) | quad) ^ rsw) * 8];
            #pragma unroll
            for (int ct = 0; ct < 2; ++ct)
                bfr[ct] = *(const bf16x8*)&sB[pb][(wn + ct * 16 + l16) * 64
                          + (((kk << 2) | quad) ^ rsw) * 8];
            #pragma unroll
            for (int rt = 0; rt < 4; ++rt)
                #pragma unroll
                for (int ct = 0; ct < 2; ++ct)
                    acc[rt][ct] = __builtin_amdgcn_mfma_f32_16x16x32_bf16(
                        af[rt], bfr[ct], acc[rt][ct], 0, 0, 0);
        }
    }

    #pragma unroll
    for (int rt = 0; rt < 4; ++rt) {
        #pragma unroll
        for (int ct = 0; ct < 2; ++ct) {
            #pragma unroll
            for (int reg = 0; reg < 4; ++reg) {
                const long row = m0 + wm + rt * 16 + quad * 4 + reg;
                const long col = n0 + wn + ct * 16 + l16;
                C[row * EMB + col] = acc[rt][ct][reg];
            }
        }
    }
}

// ---------------- MFMA flash attention: TQ=128, dbuf 64-key pipeline ----------------
// R11 flash = R10's T15-lite (stream-sequential PV: softmax1 VALU overlaps PV0
// MFMAs; vf held in regs) on R9's proven dbuf schedule. This round isolates its
// delta vs R9's 46.8us (R10's proj regression masked it). Pre-commit: >=48.5 ->
// revert to R9 flash.
#define KLD 64   // K/V LDS row stride (shorts) — linear, swizzle in chunk index
#define PLD 72   // P buffer row stride (shorts)

// stage one 64-key tile of K and V (512 chunks each, 2+2 gl_lds per thread)
__device__ inline void stage_kv64(const short* __restrict__ Kb,
                                  const short* __restrict__ Vtb,
                                  long base, int jb2,
                                  short* skp, short* svp,
                                  int tid, int wave)
{
    #pragma unroll
    for (int c = 0; c < 2; ++c) {
        const int cc  = c * 256 + tid;        // 0..511
        const int row = cc >> 3;              // 0..63
        const int sch = (cc & 7) ^ (row & 7); // pre-swizzled source chunk
        // LDS dest: wave-uniform chunk base (c*256 + wave*64); HW adds lane*16B.
        gl_lds16(Kb + base + (long)(jb2 + row) * HD + sch * 8,
                 skp + ((c * 256 + wave * 64) << 3));
        gl_lds16(Vtb + base + ((long)row << 11) + jb2 + sch * 8,
                 svp + ((c * 256 + wave * 64) << 3));
    }
}

__global__ __launch_bounds__(256, 2)
void flash_attn_mfma(const short* __restrict__ Qb,
                     const short* __restrict__ Kb,
                     const short* __restrict__ Vtb,
                     short* __restrict__ ctx)
{
    // id -> (xcd residue r, pair p, 128-query tile t)
    const int id  = blockIdx.x;           // 0..511
    const int hi  = id >> 8;              // 0 = heavy half, 1 = light half
    const int idx = id & 255;
    const int r   = idx & 7;              // XCD residue
    const int s5  = idx >> 3;             // 0..31
    const int pi  = s5 & 3;               // pair-within-residue
    const int ts8 = s5 >> 2;              // 0..7
    const int p   = r + 8 * pi;           // (b*NH+h) in [0,32)
    const int b   = p >> 4, h = p & 15;
    const int t   = hi ? ts8 : (15 - ts8);

    const int tid = threadIdx.x;
    const int wave = tid >> 6, lane = tid & 63;
    const int quad = lane >> 4, l16 = lane & 15;
    const int r0 = t * 128;

    __shared__ short sk[2][64 * KLD];     // double-buffered K (16 KB)
    __shared__ short sv[2][64 * KLD];     // double-buffered V (16 KB)
    __shared__ short sp[4][32 * PLD];     // per-wave P: rows 0..15 g0, 16..31 g1 (18 KB)

    const long base = ((long)(b * NH + h)) << 17;   // SEQ*HD = 2^17

    // two 16-query groups per wave (contiguous): iq1 = iq0 + 16
    const int iq0 = r0 + wave * 32 + l16;
    const int iq1 = iq0 + 16;
    const int dtile = 2 * t + (wave >> 1);   // this wave's diagonal 64-key tile
    const int rsw = l16 & 7;                 // read-side swizzle (row&7 == l16&7)

    bf16x8 qf0[2], qf1[2];
    #pragma unroll
    for (int tt = 0; tt < 2; ++tt) {
        qf0[tt] = *(const bf16x8*)(Qb + base + (long)iq0 * HD + tt * 32 + quad * 8);
        qf1[tt] = *(const bf16x8*)(Qb + base + (long)iq1 * HD + tt * 32 + quad * 8);
    }

    f32x4 acc0[4], acc1[4];
    #pragma unroll
    for (int ct = 0; ct < 4; ++ct) {
        acc0[ct] = (f32x4){0.f, 0.f, 0.f, 0.f};
        acc1[ct] = (f32x4){0.f, 0.f, 0.f, 0.f};
    }
    float m0 = MINIT, l0 = 0.f;
    float m1 = MINIT, l1 = 0.f;

    const int J = 2 * t + 2;              // 64-key tiles to process (block-uniform)

    stage_kv64(Kb, Vtb, base, 0, sk[0], sv[0], tid, wave);

    #pragma unroll 1
    for (int j2 = 0; j2 < J; ++j2) {
        const int pb = j2 & 1;
        // own loads of buf[pb] (issued a full tile ago) complete, then sync:
        asm volatile("s_waitcnt vmcnt(0)" ::: "memory");
        __builtin_amdgcn_s_barrier();
        // issue next tile's loads into the other buffer (retire under compute)
        if (j2 + 1 < J)
            stage_kv64(Kb, Vtb, base, (j2 + 1) * 64,
                       sk[pb ^ 1], sv[pb ^ 1], tid, wave);

        if (j2 <= dtile) {
            const int jb2 = j2 * 64;
            const short* skh = sk[pb];
            const short* svh = sv[pb];

            // S^T for both groups; K fragments per-ct, shared by both groups.
            f32x4 s0[4], s1[4];
            __builtin_amdgcn_s_setprio(1);
            #pragma unroll
            for (int ct = 0; ct < 4; ++ct) {
                const int rr16 = (ct * 16 + l16) * KLD;
                bf16x8 k0 = *(const bf16x8*)&skh[rr16 + ((quad ^ rsw) << 3)];
                bf16x8 k1 = *(const bf16x8*)&skh[rr16 + (((4 + quad) ^ rsw) << 3)];
                f32x4 z0 = (f32x4){0.f, 0.f, 0.f, 0.f};
                z0 = __builtin_amdgcn_mfma_f32_16x16x32_bf16(k0, qf0[0], z0, 0, 0, 0);
                z0 = __builtin_amdgcn_mfma_f32_16x16x32_bf16(k1, qf0[1], z0, 0, 0, 0);
                s0[ct] = z0;
                f32x4 z1 = (f32x4){0.f, 0.f, 0.f, 0.f};
                z1 = __builtin_amdgcn_mfma_f32_16x16x32_bf16(k0, qf1[0], z1, 0, 0, 0);
                z1 = __builtin_amdgcn_mfma_f32_16x16x32_bf16(k1, qf1[1], z1, 0, 0, 0);
                s1[ct] = z1;
            }
            __builtin_amdgcn_s_setprio(0);

            if (j2 == dtile) {   // diagonal tile: causal mask per group
                #pragma unroll
                for (int ct = 0; ct < 4; ++ct)
                    #pragma unroll
                    for (int rr = 0; rr < 4; ++rr) {
                        const int j = jb2 + ct * 16 + quad * 4 + rr;
                        if (!((j < iq0) || (iq0 == 0 && j == 0)))
                            s0[ct][rr] = -INFINITY;
                        if (!(j < iq1))               // iq1 >= 16, no (0,0) case
                            s1[ct][rr] = -INFINITY;
                    }
            }

            // ---- stream 0: softmax -> P0 -> rescale -> PV0 (vf held in regs) ----
            float mx0 = MINIT;
            #pragma unroll
            for (int ct = 0; ct < 4; ++ct)
                #pragma unroll
                for (int rr = 0; rr < 4; ++rr) mx0 = fmaxf(mx0, s0[ct][rr]);
            mx0 = fmaxf(mx0, __shfl_xor(mx0, 16, 64));
            mx0 = fmaxf(mx0, __shfl_xor(mx0, 32, 64));
            const float mn0 = fmaxf(m0, mx0);
            const float a0 = fexp2(m0 - mn0);
            m0 = mn0;
            float ss0 = 0.f;
            #pragma unroll
            for (int ct = 0; ct < 4; ++ct)
                #pragma unroll
                for (int rr = 0; rr < 4; ++rr) {
                    const float e = fexp2(s0[ct][rr] - mn0);
                    s0[ct][rr] = e;
                    ss0 += e;
                }
            ss0 += __shfl_xor(ss0, 16, 64);
            ss0 += __shfl_xor(ss0, 32, 64);
            l0 = l0 * a0 + ss0;

            short* pw0 = sp[wave];
            #pragma unroll
            for (int ct = 0; ct < 4; ++ct) {
                short4 p4;
                p4.x = f2bf(s0[ct][0]); p4.y = f2bf(s0[ct][1]);
                p4.z = f2bf(s0[ct][2]); p4.w = f2bf(s0[ct][3]);
                *(short4*)&pw0[l16 * PLD + ct * 16 + quad * 4] = p4;
            }
            #pragma unroll
            for (int ct = 0; ct < 4; ++ct)
                #pragma unroll
                for (int rr = 0; rr < 4; ++rr) acc0[ct][rr] *= a0;

            bf16x8 pf00 = *(const bf16x8*)&pw0[l16 * PLD + quad * 8];
            bf16x8 pf01 = *(const bf16x8*)&pw0[l16 * PLD + 32 + quad * 8];

            bf16x8 vf[4][2];
            __builtin_amdgcn_s_setprio(1);
            #pragma unroll
            for (int ct = 0; ct < 4; ++ct) {
                const int rr16 = (ct * 16 + l16) * KLD;
                vf[ct][0] = *(const bf16x8*)&svh[rr16 + ((quad ^ rsw) << 3)];
                vf[ct][1] = *(const bf16x8*)&svh[rr16 + (((4 + quad) ^ rsw) << 3)];
                acc0[ct] = __builtin_amdgcn_mfma_f32_16x16x32_bf16(
                    vf[ct][0], pf00, acc0[ct], 0, 0, 0);
                acc0[ct] = __builtin_amdgcn_mfma_f32_16x16x32_bf16(
                    vf[ct][1], pf01, acc0[ct], 0, 0, 0);
            }
            __builtin_amdgcn_s_setprio(0);

            // ---- stream 1: softmax VALU overlaps PV0 MFMAs in flight ----
            float mx1 = MINIT;
            #pragma unroll
            for (int ct = 0; ct < 4; ++ct)
                #pragma unroll
                for (int rr = 0; rr < 4; ++rr) mx1 = fmaxf(mx1, s1[ct][rr]);
            mx1 = fmaxf(mx1, __shfl_xor(mx1, 16, 64));
            mx1 = fmaxf(mx1, __shfl_xor(mx1, 32, 64));
            const float mn1 = fmaxf(m1, mx1);
            const float a1 = fexp2(m1 - mn1);
            m1 = mn1;
            float ss1 = 0.f;
            #pragma unroll
            for (int ct = 0; ct < 4; ++ct)
                #pragma unroll
                for (int rr = 0; rr < 4; ++rr) {
                    const float e = fexp2(s1[ct][rr] - mn1);
                    s1[ct][rr] = e;
                    ss1 += e;
                }
            ss1 += __shfl_xor(ss1, 16, 64);
            ss1 += __shfl_xor(ss1, 32, 64);
            l1 = l1 * a1 + ss1;

            short* pw1 = sp[wave] + 16 * PLD;
            #pragma unroll
            for (int ct = 0; ct < 4; ++ct) {
                short4 q4;
                q4.x = f2bf(s1[ct][0]); q4.y = f2bf(s1[ct][1]);
                q4.z = f2bf(s1[ct][2]); q4.w = f2bf(s1[ct][3]);
                *(short4*)&pw1[l16 * PLD + ct * 16 + quad * 4] = q4;
            }
            #pragma unroll
            for (int ct = 0; ct < 4; ++ct)
                #pragma unroll
                for (int rr = 0; rr < 4; ++rr) acc1[ct][rr] *= a1;

            bf16x8 pf10 = *(const bf16x8*)&pw1[l16 * PLD + quad * 8];
            bf16x8 pf11 = *(const bf16x8*)&pw1[l16 * PLD + 32 + quad * 8];

            __builtin_amdgcn_s_setprio(1);
            #pragma unroll
            for (int ct = 0; ct < 4; ++ct) {
                acc1[ct] = __builtin_amdgcn_mfma_f32_16x16x32_bf16(
                    vf[ct][0], pf10, acc1[ct], 0, 0, 0);
                acc1[ct] = __builtin_amdgcn_mfma_f32_16x16x32_bf16(
                    vf[ct][1], pf11, acc1[ct], 0, 0, 0);
            }
            __builtin_amdgcn_s_setprio(0);
        }
    }

    // epilogue: acc C-layout row=dim (ct*16+quad*4+reg), col=l16=query
    {
        const float inv0 = 1.f / l0;
        short* orow = ctx + (long)(b * SEQ + iq0) * DATTN + h * HD;
        #pragma unroll
        for (int ct = 0; ct < 4; ++ct) {
            short4 o4;
            o4.x = f2bf(acc0[ct][0] * inv0);
            o4.y = f2bf(acc0[ct][1] * inv0);
            o4.z = f2bf(acc0[ct][2] * inv0);
            o4.w = f2bf(acc0[ct][3] * inv0);
            *(short4*)&orow[ct * 16 + quad * 4] = o4;
        }
    }
    {
        const float inv1 = 1.f / l1;
        short* orow = ctx + (long)(b * SEQ + iq1) * DATTN + h * HD;
        #pragma unroll
        for (int ct = 0; ct < 4; ++ct) {
            short4 o4;
            o4.x = f2bf(acc1[ct][0] * inv1);
            o4.y = f2bf(acc1[ct][1] * inv1);
            o4.z = f2bf(acc1[ct][2] * inv1);
            o4.w = f2bf(acc1[ct][3] * inv1);
            *(short4*)&orow[ct * 16 + quad * 4] = o4;
        }
    }
}

extern "C" void kernel_launch(void* const* d_in, const int* in_sizes, int n_in,
                              void* d_out, int out_size, void* d_ws, size_t ws_size,
                              hipStream_t stream) {
    const float* q  = (const float*)d_in[0];
    const float* k  = (const float*)d_in[1];
    const float* v  = (const float*)d_in[2];
    const float* Wq = (const float*)d_in[3];
    const float* Wk = (const float*)d_in[4];
    const float* Wv = (const float*)d_in[5];
    const float* Wo = (const float*)d_in[6];
    float* out = (float*)d_out;

    // workspace (bf16 shorts), 64 MB:
    // qb|kb|vb (4M shorts each) | wqb|wkb|wvb|wob (1M each) | Qb|Kb|Vtb|ctx (4M each)
    const long QKV = (long)MM * EMB;      // 4,194,304
    const long WSZ = (long)DATTN * EMB;   // 1,048,576
    short* basep = (short*)d_ws;
    short* qb  = basep;
    short* kb  = qb + QKV;
    short* vb  = kb + QKV;
    short* wqb = vb + QKV;
    short* wkb = wqb + WSZ;
    short* wvb = wkb + WSZ;
    short* wob = wvb + WSZ;
    short* Qb  = wob + WSZ;
    short* Kb  = Qb + QKV;
    short* Vtb = Kb + QKV;
    short* ctx = Vtb + QKV;

    // 1) fp32 -> bf16 pre-convert (all 7 tensors — R9 factorization restored)
    cvt_all<<<16384, 256, 0, stream>>>(q, k, v, Wq, Wk, Wv, Wo, qb);

    // 2) fused Q/K/V projection + RoPE (BK=64, swizzled gl_lds staging, R9)
    gemm_proj_bf16<<<dim3(MM / 128, DATTN / 128, 3), 256, 0, stream>>>(
        qb, kb, vb, wqb, wkb, wvb, Qb, Kb, Vtb);

    // 3) flash attention (R9 dbuf schedule + T15-lite stream-sequential PV)
    flash_attn_mfma<<<512, 256, 0, stream>>>(Qb, Kb, Vtb, ctx);

    // 4) output GEMM (128x64 tiles, BK=64 swizzled, dbuf pipeline, 512 blocks)
    gemm_out_bf16<<<dim3(MM / 128, EMB / 64), 256, 0, stream>>>(ctx, wob, out);
}